// Round 1
// baseline (790.586 us; speedup 1.0000x reference)
//
#include <hip/hip_runtime.h>

#define D 128
#define DA 16
#define EPW 8

// ---------------------------------------------------------------------------
// Kernel 1: h0 = x@W0 + b0 ; h1 = x@W1 + b1   (fused: x tile read once)
// 64 rows/block, 256 threads, K chunked by 32. Per thread: 8 rows x 4 cols x 2 mats.
// ---------------------------------------------------------------------------
__global__ __launch_bounds__(256) void node_transform_kernel(
    const float* __restrict__ x, const float* __restrict__ W0, const float* __restrict__ b0,
    const float* __restrict__ W1, const float* __restrict__ b1,
    float* __restrict__ h0, float* __restrict__ h1, int N)
{
    __shared__ __align__(16) float xs[64][32];
    __shared__ __align__(16) float w0s[32][128];
    __shared__ __align__(16) float w1s[32][128];
    const int t = threadIdx.x;
    const int row0 = blockIdx.x * 64;
    const int cg = (t & 31) * 4;   // 4 output cols
    const int rg = (t >> 5) * 8;   // 8 output rows
    float4 acc0[8], acc1[8];
    #pragma unroll
    for (int i = 0; i < 8; i++) { acc0[i] = make_float4(0,0,0,0); acc1[i] = make_float4(0,0,0,0); }

    for (int kc = 0; kc < D; kc += 32) {
        // stage x tile (64x32)
        #pragma unroll
        for (int i = 0; i < 2; i++) {
            int ff = t + i * 256;          // float4 index over 512
            int r = ff >> 3;
            int k = (ff & 7) * 4;
            int gr = row0 + r;
            float4 v = make_float4(0,0,0,0);
            if (gr < N) v = *(const float4*)(x + (size_t)gr * D + kc + k);
            *(float4*)&xs[r][k] = v;
        }
        // stage W0/W1 chunks (32x128 each)
        #pragma unroll
        for (int i = 0; i < 4; i++) {
            int ff = t + i * 256;          // float4 index over 1024
            int k = ff >> 5;
            int c = (ff & 31) * 4;
            *(float4*)&w0s[k][c] = *(const float4*)(W0 + (size_t)(kc + k) * D + c);
            *(float4*)&w1s[k][c] = *(const float4*)(W1 + (size_t)(kc + k) * D + c);
        }
        __syncthreads();
        #pragma unroll 4
        for (int k = 0; k < 32; k++) {
            float4 wv0 = *(float4*)&w0s[k][cg];
            float4 wv1 = *(float4*)&w1s[k][cg];
            #pragma unroll
            for (int i = 0; i < 8; i++) {
                float xv = xs[rg + i][k];
                acc0[i].x += xv * wv0.x; acc0[i].y += xv * wv0.y;
                acc0[i].z += xv * wv0.z; acc0[i].w += xv * wv0.w;
                acc1[i].x += xv * wv1.x; acc1[i].y += xv * wv1.y;
                acc1[i].z += xv * wv1.z; acc1[i].w += xv * wv1.w;
            }
        }
        __syncthreads();
    }
    const float4 bb0 = *(const float4*)(b0 + cg);
    const float4 bb1 = *(const float4*)(b1 + cg);
    #pragma unroll
    for (int i = 0; i < 8; i++) {
        int gr = row0 + rg + i;
        if (gr < N) {
            float4 o0 = make_float4(acc0[i].x + bb0.x, acc0[i].y + bb0.y,
                                    acc0[i].z + bb0.z, acc0[i].w + bb0.w);
            float4 o1 = make_float4(acc1[i].x + bb1.x, acc1[i].y + bb1.y,
                                    acc1[i].z + bb1.z, acc1[i].w + bb1.w);
            *(float4*)(h0 + (size_t)gr * D + cg) = o0;
            *(float4*)(h1 + (size_t)gr * D + cg) = o1;
        }
    }
}

// ---------------------------------------------------------------------------
// Kernel 2: per edge e: msg = relu(h0[src0] + h1[src1] + a[e]@Wa + ba);
//           atomicAdd into agg[dst]. One wave per edge, lane handles 2 dims.
// ---------------------------------------------------------------------------
__global__ __launch_bounds__(256) void edge_kernel(
    const int* __restrict__ idx, const float* __restrict__ a,
    const float* __restrict__ Wa, const float* __restrict__ ba,
    const float* __restrict__ h0, const float* __restrict__ h1,
    float* __restrict__ agg, int E)
{
    const int lane = threadIdx.x & 63;
    const int wid  = blockIdx.x * (blockDim.x >> 6) + (threadIdx.x >> 6);
    const int c2 = lane * 2;

    // cache Wa columns (2 per lane) in registers: 16 x float2
    float2 waT[DA];
    #pragma unroll
    for (int j = 0; j < DA; j++) waT[j] = *(const float2*)(Wa + j * D + c2);
    const float2 bav = *(const float2*)(ba + c2);

    const long e0 = (long)wid * EPW;
    #pragma unroll 2
    for (int i = 0; i < EPW; i++) {
        long e = e0 + i;
        if (e >= E) break;
        int dst = idx[e];
        int s0  = idx[(long)E + e];
        int s1  = idx[2L * E + e];
        float av = a[e * DA + (lane & 15)];   // each 16-lane group holds full a[e]
        float2 h0v = *(const float2*)(h0 + (size_t)s0 * D + c2);
        float2 h1v = *(const float2*)(h1 + (size_t)s1 * D + c2);
        float mx = h0v.x + h1v.x + bav.x;
        float my = h0v.y + h1v.y + bav.y;
        #pragma unroll
        for (int j = 0; j < DA; j++) {
            float aj = __shfl(av, j, 16);
            mx += aj * waT[j].x;
            my += aj * waT[j].y;
        }
        mx = fmaxf(mx, 0.0f);
        my = fmaxf(my, 0.0f);
        float* p = agg + (size_t)dst * D + c2;
        atomicAdd(p,     mx);
        atomicAdd(p + 1, my);
    }
}

// ---------------------------------------------------------------------------
// Kernel 3: h = x*(1+eps)+agg ; t = relu(h@W_in+b_in) ; out = t@W_out+b_out
// Fused: T tile stays in LDS between the two GEMMs.
// ---------------------------------------------------------------------------
__global__ __launch_bounds__(256) void mlp_kernel(
    const float* __restrict__ x, const float* __restrict__ agg, const float* __restrict__ epsp,
    const float* __restrict__ Win, const float* __restrict__ bin,
    const float* __restrict__ Wout, const float* __restrict__ bout,
    float* __restrict__ out, int N)
{
    __shared__ __align__(16) float hs[64][32];
    __shared__ __align__(16) float ws[32][128];
    __shared__ __align__(16) float ts[64][128];
    const int t = threadIdx.x;
    const int row0 = blockIdx.x * 64;
    const int cg = (t & 31) * 4;
    const int rg = (t >> 5) * 8;
    const float epsv = 1.0f + epsp[0];
    float4 acc[8];
    #pragma unroll
    for (int i = 0; i < 8; i++) acc[i] = make_float4(0,0,0,0);

    // ---- phase 1: T = relu((x*(1+eps)+agg) @ Win + bin) ----
    for (int kc = 0; kc < D; kc += 32) {
        #pragma unroll
        for (int i = 0; i < 2; i++) {
            int ff = t + i * 256;
            int r = ff >> 3;
            int k = (ff & 7) * 4;
            int gr = row0 + r;
            float4 v = make_float4(0,0,0,0);
            if (gr < N) {
                float4 xv = *(const float4*)(x   + (size_t)gr * D + kc + k);
                float4 gv = *(const float4*)(agg + (size_t)gr * D + kc + k);
                v = make_float4(xv.x * epsv + gv.x, xv.y * epsv + gv.y,
                                xv.z * epsv + gv.z, xv.w * epsv + gv.w);
            }
            *(float4*)&hs[r][k] = v;
        }
        #pragma unroll
        for (int i = 0; i < 4; i++) {
            int ff = t + i * 256;
            int k = ff >> 5;
            int c = (ff & 31) * 4;
            *(float4*)&ws[k][c] = *(const float4*)(Win + (size_t)(kc + k) * D + c);
        }
        __syncthreads();
        #pragma unroll 4
        for (int k = 0; k < 32; k++) {
            float4 wv = *(float4*)&ws[k][cg];
            #pragma unroll
            for (int i = 0; i < 8; i++) {
                float hv = hs[rg + i][k];
                acc[i].x += hv * wv.x; acc[i].y += hv * wv.y;
                acc[i].z += hv * wv.z; acc[i].w += hv * wv.w;
            }
        }
        __syncthreads();
    }
    {
        const float4 bb = *(const float4*)(bin + cg);
        #pragma unroll
        for (int i = 0; i < 8; i++) {
            float4 tv = make_float4(fmaxf(acc[i].x + bb.x, 0.0f), fmaxf(acc[i].y + bb.y, 0.0f),
                                    fmaxf(acc[i].z + bb.z, 0.0f), fmaxf(acc[i].w + bb.w, 0.0f));
            *(float4*)&ts[rg + i][cg] = tv;
            acc[i] = make_float4(0,0,0,0);
        }
    }
    __syncthreads();

    // ---- phase 2: out = T @ Wout + bout ----
    for (int kc = 0; kc < D; kc += 32) {
        #pragma unroll
        for (int i = 0; i < 4; i++) {
            int ff = t + i * 256;
            int k = ff >> 5;
            int c = (ff & 31) * 4;
            *(float4*)&ws[k][c] = *(const float4*)(Wout + (size_t)(kc + k) * D + c);
        }
        __syncthreads();
        #pragma unroll 4
        for (int k = 0; k < 32; k++) {
            float4 wv = *(float4*)&ws[k][cg];
            #pragma unroll
            for (int i = 0; i < 8; i++) {
                float tv = ts[rg + i][kc + k];
                acc[i].x += tv * wv.x; acc[i].y += tv * wv.y;
                acc[i].z += tv * wv.z; acc[i].w += tv * wv.w;
            }
        }
        __syncthreads();
    }
    const float4 bo = *(const float4*)(bout + cg);
    #pragma unroll
    for (int i = 0; i < 8; i++) {
        int gr = row0 + rg + i;
        if (gr < N) {
            float4 o = make_float4(acc[i].x + bo.x, acc[i].y + bo.y,
                                   acc[i].z + bo.z, acc[i].w + bo.w);
            *(float4*)(out + (size_t)gr * D + cg) = o;
        }
    }
}

extern "C" void kernel_launch(void* const* d_in, const int* in_sizes, int n_in,
                              void* d_out, int out_size, void* d_ws, size_t ws_size,
                              hipStream_t stream)
{
    const float* x    = (const float*)d_in[0];
    const int*   idx  = (const int*)  d_in[1];
    const float* a    = (const float*)d_in[2];
    const float* W0   = (const float*)d_in[3];
    const float* b0   = (const float*)d_in[4];
    const float* W1   = (const float*)d_in[5];
    const float* b1   = (const float*)d_in[6];
    const float* Wa   = (const float*)d_in[7];
    const float* ba   = (const float*)d_in[8];
    const float* eps  = (const float*)d_in[9];
    const float* Win  = (const float*)d_in[10];
    const float* bin  = (const float*)d_in[11];
    const float* Wout = (const float*)d_in[12];
    const float* bout = (const float*)d_in[13];
    float* out = (float*)d_out;

    const int N = in_sizes[0] / D;
    const int E = in_sizes[1] / 3;

    float* agg = (float*)d_ws;
    float* h0  = agg + (size_t)N * D;
    float* h1  = h0  + (size_t)N * D;

    hipMemsetAsync(agg, 0, (size_t)N * D * sizeof(float), stream);

    const int nblk = (N + 63) / 64;
    node_transform_kernel<<<nblk, 256, 0, stream>>>(x, W0, b0, W1, b1, h0, h1, N);

    const int eblk = (E + 4 * EPW - 1) / (4 * EPW);
    edge_kernel<<<eblk, 256, 0, stream>>>(idx, a, Wa, ba, h0, h1, agg, E);

    mlp_kernel<<<nblk, 256, 0, stream>>>(x, agg, eps, Win, bin, Wout, bout, out, N);
}

// Round 3
// 516.024 us; speedup vs baseline: 1.5321x; 1.5321x over previous
//
#include <hip/hip_runtime.h>

#define D 128
#define DA 16

// ---------------------------------------------------------------------------
// Kernel 1: h0 = x@W0 + b0 ; h1 = x@W1 + b1   (fused: x tile read once)
// ---------------------------------------------------------------------------
__global__ __launch_bounds__(256) void node_transform_kernel(
    const float* __restrict__ x, const float* __restrict__ W0, const float* __restrict__ b0,
    const float* __restrict__ W1, const float* __restrict__ b1,
    float* __restrict__ h0, float* __restrict__ h1, int N)
{
    __shared__ __align__(16) float xs[64][32];
    __shared__ __align__(16) float w0s[32][128];
    __shared__ __align__(16) float w1s[32][128];
    const int t = threadIdx.x;
    const int row0 = blockIdx.x * 64;
    const int cg = (t & 31) * 4;   // 4 output cols
    const int rg = (t >> 5) * 8;   // 8 output rows
    float4 acc0[8], acc1[8];
    #pragma unroll
    for (int i = 0; i < 8; i++) { acc0[i] = make_float4(0,0,0,0); acc1[i] = make_float4(0,0,0,0); }

    for (int kc = 0; kc < D; kc += 32) {
        #pragma unroll
        for (int i = 0; i < 2; i++) {
            int ff = t + i * 256;
            int r = ff >> 3;
            int k = (ff & 7) * 4;
            int gr = row0 + r;
            float4 v = make_float4(0,0,0,0);
            if (gr < N) v = *(const float4*)(x + (size_t)gr * D + kc + k);
            *(float4*)&xs[r][k] = v;
        }
        #pragma unroll
        for (int i = 0; i < 4; i++) {
            int ff = t + i * 256;
            int k = ff >> 5;
            int c = (ff & 31) * 4;
            *(float4*)&w0s[k][c] = *(const float4*)(W0 + (size_t)(kc + k) * D + c);
            *(float4*)&w1s[k][c] = *(const float4*)(W1 + (size_t)(kc + k) * D + c);
        }
        __syncthreads();
        #pragma unroll 4
        for (int k = 0; k < 32; k++) {
            float4 wv0 = *(float4*)&w0s[k][cg];
            float4 wv1 = *(float4*)&w1s[k][cg];
            #pragma unroll
            for (int i = 0; i < 8; i++) {
                float xv = xs[rg + i][k];
                acc0[i].x += xv * wv0.x; acc0[i].y += xv * wv0.y;
                acc0[i].z += xv * wv0.z; acc0[i].w += xv * wv0.w;
                acc1[i].x += xv * wv1.x; acc1[i].y += xv * wv1.y;
                acc1[i].z += xv * wv1.z; acc1[i].w += xv * wv1.w;
            }
        }
        __syncthreads();
    }
    const float4 bb0 = *(const float4*)(b0 + cg);
    const float4 bb1 = *(const float4*)(b1 + cg);
    #pragma unroll
    for (int i = 0; i < 8; i++) {
        int gr = row0 + rg + i;
        if (gr < N) {
            float4 o0 = make_float4(acc0[i].x + bb0.x, acc0[i].y + bb0.y,
                                    acc0[i].z + bb0.z, acc0[i].w + bb0.w);
            float4 o1 = make_float4(acc1[i].x + bb1.x, acc1[i].y + bb1.y,
                                    acc1[i].z + bb1.z, acc1[i].w + bb1.w);
            *(float4*)(h0 + (size_t)gr * D + cg) = o0;
            *(float4*)(h1 + (size_t)gr * D + cg) = o1;
        }
    }
}

// ---------------------------------------------------------------------------
// Counting sort by dst: histogram -> single-block scan -> scatter of records
// ---------------------------------------------------------------------------
__global__ __launch_bounds__(256) void hist_kernel(
    const int* __restrict__ idx, int* __restrict__ cnt, int E)
{
    const int stride = gridDim.x * blockDim.x;
    for (int e = blockIdx.x * blockDim.x + threadIdx.x; e < E; e += stride)
        atomicAdd(&cnt[idx[e]], 1);
}

__global__ __launch_bounds__(1024) void scan_kernel(
    const int* __restrict__ cnt, int* __restrict__ offs, int* __restrict__ cursor, int N)
{
    const int t = threadIdx.x;
    const int seg = (N + 1023) >> 10;
    const int base = t * seg;
    int sum = 0;
    for (int i = 0; i < seg; i++) {
        int g = base + i;
        if (g < N) sum += cnt[g];
    }
    __shared__ int tmp[1024];
    tmp[t] = sum;
    __syncthreads();
    for (int off = 1; off < 1024; off <<= 1) {
        int v = (t >= off) ? tmp[t - off] : 0;
        __syncthreads();
        tmp[t] += v;
        __syncthreads();
    }
    int run = tmp[t] - sum;   // exclusive prefix of this thread's segment
    for (int i = 0; i < seg; i++) {
        int g = base + i;
        if (g < N) {
            offs[g] = run;
            cursor[g] = run;
            run += cnt[g];
        }
    }
    if (t == 1023) offs[N] = run;   // == E
}

__global__ __launch_bounds__(256) void scatter_kernel(
    const int* __restrict__ idx, int* __restrict__ cursor, int4* __restrict__ srt, int E)
{
    const int stride = gridDim.x * blockDim.x;
    for (int e = blockIdx.x * blockDim.x + threadIdx.x; e < E; e += stride) {
        int dst = idx[e];
        int s0  = idx[(long)E + e];
        int s1  = idx[2L * E + e];
        int pos = atomicAdd(&cursor[dst], 1);
        srt[pos] = make_int4(e, s0, s1, 0);
    }
}

// ---------------------------------------------------------------------------
// Kernel 2 (pull): per node d, wave walks its dst-sorted edge bucket:
//   acc += relu(h0[s0] + h1[s1] + a[e]@Wa + ba); plain store of agg row.
// No float atomics. Lane = 2 dims. Next-record prefetch pipeline.
// ---------------------------------------------------------------------------
__global__ __launch_bounds__(256) void pull_kernel(
    const int4* __restrict__ srt, const int* __restrict__ offs,
    const float* __restrict__ a, const float* __restrict__ Wa, const float* __restrict__ ba,
    const float* __restrict__ h0, const float* __restrict__ h1,
    float* __restrict__ agg, int N)
{
    const int lane = threadIdx.x & 63;
    const int wid  = blockIdx.x * (blockDim.x >> 6) + (threadIdx.x >> 6);
    if (wid >= N) return;
    const int c2 = lane * 2;

    float2 waT[DA];
    #pragma unroll
    for (int j = 0; j < DA; j++) waT[j] = *(const float2*)(Wa + j * D + c2);
    const float2 bav = *(const float2*)(ba + c2);

    const int start = offs[wid];
    const int end   = offs[wid + 1];

    float accx = 0.0f, accy = 0.0f;

    int4  rec = make_int4(0, 0, 0, 0);
    float av  = 0.0f;
    if (start < end) {
        rec = srt[start];
        av  = a[(long)rec.x * DA + (lane & 15)];
    }
    for (int ei = start; ei < end; ei++) {
        const int   s0  = rec.y;
        const int   s1  = rec.z;
        const float avc = av;
        if (ei + 1 < end) {                       // prefetch next record
            rec = srt[ei + 1];
            av  = a[(long)rec.x * DA + (lane & 15)];
        }
        float2 h0v = *(const float2*)(h0 + (size_t)s0 * D + c2);
        float2 h1v = *(const float2*)(h1 + (size_t)s1 * D + c2);
        float mx = h0v.x + h1v.x + bav.x;
        float my = h0v.y + h1v.y + bav.y;
        #pragma unroll
        for (int j = 0; j < DA; j++) {
            float aj = __shfl(avc, j, 16);
            mx += aj * waT[j].x;
            my += aj * waT[j].y;
        }
        accx += fmaxf(mx, 0.0f);
        accy += fmaxf(my, 0.0f);
    }
    *(float2*)(agg + (size_t)wid * D + c2) = make_float2(accx, accy);
}

// ---------------------------------------------------------------------------
// Kernel 3: h = x*(1+eps)+agg ; t = relu(h@W_in+b_in) ; out = t@W_out+b_out
// NOTE: agg aliases out (agg lives in d_out) — each block reads only its own
// rows (phase 1) and writes them only at the very end. No __restrict__ on
// agg/out.
// ---------------------------------------------------------------------------
__global__ __launch_bounds__(256) void mlp_kernel(
    const float* __restrict__ x, const float* agg, const float* __restrict__ epsp,
    const float* __restrict__ Win, const float* __restrict__ bin,
    const float* __restrict__ Wout, const float* __restrict__ bout,
    float* out, int N)
{
    __shared__ __align__(16) float hs[64][32];
    __shared__ __align__(16) float ws[32][128];
    __shared__ __align__(16) float ts[64][128];
    const int t = threadIdx.x;
    const int row0 = blockIdx.x * 64;
    const int cg = (t & 31) * 4;
    const int rg = (t >> 5) * 8;
    const float epsv = 1.0f + epsp[0];
    float4 acc[8];
    #pragma unroll
    for (int i = 0; i < 8; i++) acc[i] = make_float4(0,0,0,0);

    // ---- phase 1: T = relu((x*(1+eps)+agg) @ Win + bin) ----
    for (int kc = 0; kc < D; kc += 32) {
        #pragma unroll
        for (int i = 0; i < 2; i++) {
            int ff = t + i * 256;
            int r = ff >> 3;
            int k = (ff & 7) * 4;
            int gr = row0 + r;
            float4 v = make_float4(0,0,0,0);
            if (gr < N) {
                float4 xv = *(const float4*)(x   + (size_t)gr * D + kc + k);
                float4 gv = *(const float4*)(agg + (size_t)gr * D + kc + k);
                v = make_float4(xv.x * epsv + gv.x, xv.y * epsv + gv.y,
                                xv.z * epsv + gv.z, xv.w * epsv + gv.w);
            }
            *(float4*)&hs[r][k] = v;
        }
        #pragma unroll
        for (int i = 0; i < 4; i++) {
            int ff = t + i * 256;
            int k = ff >> 5;
            int c = (ff & 31) * 4;
            *(float4*)&ws[k][c] = *(const float4*)(Win + (size_t)(kc + k) * D + c);
        }
        __syncthreads();
        #pragma unroll 4
        for (int k = 0; k < 32; k++) {
            float4 wv = *(float4*)&ws[k][cg];
            #pragma unroll
            for (int i = 0; i < 8; i++) {
                float hv = hs[rg + i][k];
                acc[i].x += hv * wv.x; acc[i].y += hv * wv.y;
                acc[i].z += hv * wv.z; acc[i].w += hv * wv.w;
            }
        }
        __syncthreads();
    }
    {
        const float4 bb = *(const float4*)(bin + cg);
        #pragma unroll
        for (int i = 0; i < 8; i++) {
            float4 tv = make_float4(fmaxf(acc[i].x + bb.x, 0.0f), fmaxf(acc[i].y + bb.y, 0.0f),
                                    fmaxf(acc[i].z + bb.z, 0.0f), fmaxf(acc[i].w + bb.w, 0.0f));
            *(float4*)&ts[rg + i][cg] = tv;
            acc[i] = make_float4(0,0,0,0);
        }
    }
    __syncthreads();

    // ---- phase 2: out = T @ Wout + bout ----
    for (int kc = 0; kc < D; kc += 32) {
        #pragma unroll
        for (int i = 0; i < 4; i++) {
            int ff = t + i * 256;
            int k = ff >> 5;
            int c = (ff & 31) * 4;
            *(float4*)&ws[k][c] = *(const float4*)(Wout + (size_t)(kc + k) * D + c);
        }
        __syncthreads();
        #pragma unroll 4
        for (int k = 0; k < 32; k++) {
            float4 wv = *(float4*)&ws[k][cg];
            #pragma unroll
            for (int i = 0; i < 8; i++) {
                float tv = ts[rg + i][kc + k];
                acc[i].x += tv * wv.x; acc[i].y += tv * wv.y;
                acc[i].z += tv * wv.z; acc[i].w += tv * wv.w;
            }
        }
        __syncthreads();
    }
    const float4 bo = *(const float4*)(bout + cg);
    #pragma unroll
    for (int i = 0; i < 8; i++) {
        int gr = row0 + rg + i;
        if (gr < N) {
            float4 o = make_float4(acc[i].x + bo.x, acc[i].y + bo.y,
                                   acc[i].z + bo.z, acc[i].w + bo.w);
            *(float4*)(out + (size_t)gr * D + cg) = o;
        }
    }
}

extern "C" void kernel_launch(void* const* d_in, const int* in_sizes, int n_in,
                              void* d_out, int out_size, void* d_ws, size_t ws_size,
                              hipStream_t stream)
{
    const float* x    = (const float*)d_in[0];
    const int*   idx  = (const int*)  d_in[1];
    const float* a    = (const float*)d_in[2];
    const float* W0   = (const float*)d_in[3];
    const float* b0   = (const float*)d_in[4];
    const float* W1   = (const float*)d_in[5];
    const float* b1   = (const float*)d_in[6];
    const float* Wa   = (const float*)d_in[7];
    const float* ba   = (const float*)d_in[8];
    const float* eps  = (const float*)d_in[9];
    const float* Win  = (const float*)d_in[10];
    const float* bin  = (const float*)d_in[11];
    const float* Wout = (const float*)d_in[12];
    const float* bout = (const float*)d_in[13];
    float* out = (float*)d_out;

    const int N = in_sizes[0] / D;
    const int E = in_sizes[1] / 3;

    // ws layout: srt records first (16B aligned), then h0/h1, then int arrays
    int4*  srt    = (int4*)d_ws;
    float* h0     = (float*)(srt + (size_t)E);
    float* h1     = h0 + (size_t)N * D;
    int*   cnt    = (int*)(h1 + (size_t)N * D);
    int*   offs   = cnt + N;
    int*   cursor = offs + N + 1;

    float* agg = out;   // agg lives in d_out; fully rewritten by pull_kernel

    hipMemsetAsync(cnt, 0, (size_t)N * sizeof(int), stream);

    const int nblk = (N + 63) / 64;
    node_transform_kernel<<<nblk, 256, 0, stream>>>(x, W0, b0, W1, b1, h0, h1, N);

    const int gsblk = 1024;
    hist_kernel<<<gsblk, 256, 0, stream>>>(idx, cnt, E);
    scan_kernel<<<1, 1024, 0, stream>>>(cnt, offs, cursor, N);
    scatter_kernel<<<gsblk, 256, 0, stream>>>(idx, cursor, srt, E);

    const int pblk = (N + 3) / 4;   // 4 waves (nodes) per 256-thread block
    pull_kernel<<<pblk, 256, 0, stream>>>(srt, offs, a, Wa, ba, h0, h1, agg, N);

    mlp_kernel<<<nblk, 256, 0, stream>>>(x, agg, eps, Win, bin, Wout, bout, out, N);
}